// Round 2
// baseline (62.676 us; speedup 1.0000x reference)
//
#include <hip/hip_runtime.h>
#include <hip/hip_cooperative_groups.h>
#include <math.h>

namespace cg = cooperative_groups;

#define ALPHA 0.2f

// Shapes fixed by harness: B=4, N=512, IN=128, OUT=64.
//
// Algebraic collapse of the reference (see R0 derivation):
//  i < 256 : e[b,i,j] = lrelu(g[b, 2i + (j>=256)]),  g = h·(a1+a2)
//  i >= 256: e[b,i,j] = lrelu(p[b,2(j%256)] + q[b,2(j%256)+1]),  indep. of i
// so softmax+PV reduces to per-batch column sums S0,S1 and one weighted sum.
//
// Single cooperative kernel, ONE grid.sync():
//  phase 1: h = X@W, per-row dots p,q,g            (64 blocks x 32 rows)
//  sync
//  phase 2: per-batch reductions, computed REDUNDANTLY by each block for its
//           own batch (16x duplication, all L2-hot) -> no second sync
//  phase 3: finalize own 32 rows + ELU

// ws layout (floats): h [0,131072) | p [131072,) | q [133120,) | g [135168,137216)

__global__ __launch_bounds__(256) void gat_fused(
    const float* __restrict__ X, const float* __restrict__ W,
    const float* __restrict__ a, float* __restrict__ h,
    float* __restrict__ p, float* __restrict__ q, float* __restrict__ g,
    float* __restrict__ out)
{
    __shared__ float Ws[128 * 64];   // 32 KB staged W
    __shared__ float red[256];
    __shared__ float ec_s[256];
    __shared__ float S0s[64], S1s[64], R2s[64];

    const int tid = threadIdx.x;

    // ---- stage W ----
    {
        const float4* W4 = (const float4*)W;
        float4* Ws4 = (float4*)Ws;
        for (int idx = tid; idx < 128 * 64 / 4; idx += 256)
            Ws4[idx] = W4[idx];
    }
    __syncthreads();

    const int baseRow = blockIdx.x * 32;      // 64 blocks x 32 rows = 2048
    const int lane = tid & 63;
    const int sub  = tid >> 6;                // 0..3
    const float a1 = a[lane], a2 = a[64 + lane];

    // ---- phase 1: GEMM + p,q,g ----
    for (int it = 0; it < 8; ++it) {
        const int row = baseRow + it * 4 + sub;
        const float4* xrow = (const float4*)(X + row * 128);
        float acc = 0.f;
#pragma unroll
        for (int k4 = 0; k4 < 32; ++k4) {
            float4 x4 = xrow[k4];
            acc = fmaf(x4.x, Ws[(k4 * 4 + 0) * 64 + lane], acc);
            acc = fmaf(x4.y, Ws[(k4 * 4 + 1) * 64 + lane], acc);
            acc = fmaf(x4.z, Ws[(k4 * 4 + 2) * 64 + lane], acc);
            acc = fmaf(x4.w, Ws[(k4 * 4 + 3) * 64 + lane], acc);
        }
        h[row * 64 + lane] = acc;
        float pv = acc * a1;
        float qv = acc * a2;
#pragma unroll
        for (int off = 32; off >= 1; off >>= 1) {
            pv += __shfl_xor(pv, off);
            qv += __shfl_xor(qv, off);
        }
        if (lane == 0) { p[row] = pv; q[row] = qv; g[row] = pv + qv; }
    }

    cg::this_grid().sync();

    // ---- phase 2: per-batch reductions (redundant per block) ----
    const int b = baseRow >> 9;
    float cc = p[b * 512 + 2 * tid] + q[b * 512 + 2 * tid + 1];
    cc = cc > 0.f ? cc : ALPHA * cc;
    red[tid] = cc; __syncthreads();
    for (int s = 128; s > 0; s >>= 1) {
        if (tid < s) red[tid] = fmaxf(red[tid], red[tid + s]);
        __syncthreads();
    }
    const float mc = red[0]; __syncthreads();
    const float ec = expf(cc - mc);
    ec_s[tid] = ec; red[tid] = ec; __syncthreads();
    for (int s = 128; s > 0; s >>= 1) {
        if (tid < s) red[tid] += red[tid + s];
        __syncthreads();
    }
    const float Z = red[0]; __syncthreads();

    const int c = tid & 63, grp = tid >> 6;
    float s0 = 0.f, s1 = 0.f, tt = 0.f;
    const float* hb = h + b * 512 * 64;
    for (int j = grp; j < 256; j += 4) {
        float h0 = hb[j * 64 + c];
        float h1 = hb[(j + 256) * 64 + c];
        s0 += h0;
        s1 += h1;
        tt = fmaf(ec_s[j], h0 + h1, tt);
    }
    red[tid] = s0; __syncthreads();
    if (grp == 0) S0s[c] = red[c] + red[64 + c] + red[128 + c] + red[192 + c];
    __syncthreads();
    red[tid] = s1; __syncthreads();
    if (grp == 0) S1s[c] = red[c] + red[64 + c] + red[128 + c] + red[192 + c];
    __syncthreads();
    red[tid] = tt; __syncthreads();
    if (grp == 0) R2s[c] = (red[c] + red[64 + c] + red[128 + c] + red[192 + c]) / (2.f * Z);
    __syncthreads();

    // ---- phase 3: finalize own 32 rows ----
    for (int it = 0; it < 8; ++it) {
        const int row = baseRow + it * 4 + sub;
        const int i = row & 511;          // uniform per block: all <256 or all >=256
        float hp;
        if (i < 256) {
            float u = g[b * 512 + 2 * i];
            float v = g[b * 512 + 2 * i + 1];
            u = u > 0.f ? u : ALPHA * u;
            v = v > 0.f ? v : ALPHA * v;
            const float m  = fmaxf(u, v);
            const float w0 = expf(u - m), w1 = expf(v - m);
            hp = (w0 * S0s[c] + w1 * S1s[c]) / (256.f * (w0 + w1));
        } else {
            hp = R2s[c];
        }
        out[row * 64 + c] = hp > 0.f ? hp : expm1f(hp);  // ELU(alpha=1)
    }
}

extern "C" void kernel_launch(void* const* d_in, const int* in_sizes, int n_in,
                              void* d_out, int out_size, void* d_ws, size_t ws_size,
                              hipStream_t stream) {
    const float* X = (const float*)d_in[0];   // (4,512,128)
    // d_in[1] = adj — dead code in the reference
    const float* W = (const float*)d_in[2];   // (128,64)
    const float* a = (const float*)d_in[3];   // (128,1)
    float* out = (float*)d_out;               // (4,512,64)

    float* ws = (float*)d_ws;
    float* h  = ws;
    float* p  = ws + 131072;
    float* q  = ws + 133120;
    float* g  = ws + 135168;

    void* args[] = { (void*)&X, (void*)&W, (void*)&a, (void*)&h,
                     (void*)&p, (void*)&q, (void*)&g, (void*)&out };
    hipLaunchCooperativeKernel((const void*)gat_fused, dim3(64), dim3(256),
                               args, 0, stream);
}

// Round 3
// 34.590 us; speedup vs baseline: 1.8119x; 1.8119x over previous
//
#include <hip/hip_runtime.h>
#include <math.h>

#define ALPHA 0.2f

// Shapes fixed by harness: B=4, N=512, IN=128, OUT=64.
//
// Algebraic collapse (verified R1/R2, absmax ~5e-4):
//  i < 256 : e[b,i,j] = lrelu(g[b, 2i + (j>=256)]),  g = p + q
//  i >= 256: e[b,i,j] = lrelu(p[b,2*(j%256)] + q[b,2*(j%256)+1]), indep of i
// New factorization: h = X@W never materialized —
//  p = X·wa1, q = X·wa2          (wa1 = W@a1, wa2 = W@a2, 128-vectors)
//  S0 = xs0@W, S1 = xs1@W        (xs0/xs1 = column sums of X row-halves)
//  T  = xt@W,  xt = sum_jj ec[jj]*(x_jj + x_{jj+256});  R2 = T/(2Z)
// => each block redundantly computes its batch's stats from X (L2-hot),
//    finalizes its own 32 output rows. 64 independent blocks, ONE launch,
//    no grid sync, no workspace.

__global__ __launch_bounds__(256) void gat_one(
    const float* __restrict__ X, const float* __restrict__ W,
    const float* __restrict__ a, float* __restrict__ out)
{
    __shared__ float wa1_s[128], wa2_s[128];
    __shared__ float p_s[512], q_s[512];
    __shared__ float ec_s[256];
    __shared__ float xw[3][4][128];     // per-wave partials: xs0, xs1, xt
    __shared__ float xsum[3][128];
    __shared__ float red4a[4], red4b[4];
    __shared__ float Sc[3][64];         // S0, S1, R2

    const int tid  = threadIdx.x;
    const int wid  = tid >> 6, lane = tid & 63;
    const int b    = blockIdx.x >> 4;       // batch
    const int chunk= blockIdx.x & 15;       // 32-row output chunk
    const float* Xb = X + b * 512 * 128;

    const float a1v = a[lane], a2v = a[64 + lane];

    // ---- phase 0: wa1 = W@a1, wa2 = W@a2 (wave-per-k, shuffle reduce) ----
    for (int t = 0; t < 32; ++t) {
        const int k = (t << 2) + wid;
        const float wv = W[k * 64 + lane];
        float r1 = wv * a1v, r2 = wv * a2v;
#pragma unroll
        for (int off = 32; off >= 1; off >>= 1) {
            r1 += __shfl_xor(r1, off);
            r2 += __shfl_xor(r2, off);
        }
        if (lane == 0) { wa1_s[k] = r1; wa2_s[k] = r2; }
    }
    __syncthreads();

    // ---- phase A: p[j] = x_j·wa1, q[j] = x_j·wa2 (lane = row, no shuffles) --
    const float4* wa14 = (const float4*)wa1_s;
    const float4* wa24 = (const float4*)wa2_s;
#pragma unroll
    for (int cc2 = 0; cc2 < 2; ++cc2) {
        const int j = wid * 128 + cc2 * 64 + lane;
        const float4* xr = (const float4*)(Xb + j * 128);
        float pp0 = 0.f, pp1 = 0.f, qq0 = 0.f, qq1 = 0.f;
#pragma unroll
        for (int k4 = 0; k4 < 32; ++k4) {
            const float4 x4 = xr[k4];
            const float4 w1 = wa14[k4];   // LDS broadcast
            const float4 w2 = wa24[k4];
            pp0 = fmaf(x4.x, w1.x, pp0); pp1 = fmaf(x4.y, w1.y, pp1);
            pp0 = fmaf(x4.z, w1.z, pp0); pp1 = fmaf(x4.w, w1.w, pp1);
            qq0 = fmaf(x4.x, w2.x, qq0); qq1 = fmaf(x4.y, w2.y, qq1);
            qq0 = fmaf(x4.z, w2.z, qq0); qq1 = fmaf(x4.w, w2.w, qq1);
        }
        p_s[j] = pp0 + pp1;
        q_s[j] = qq0 + qq1;
    }
    __syncthreads();

    // ---- phase B: softmax over cc[jj] = lrelu(p[2jj] + q[2jj+1]) ----
    float cc = p_s[2 * tid] + q_s[2 * tid + 1];
    cc = cc > 0.f ? cc : ALPHA * cc;
    float m = cc;
#pragma unroll
    for (int off = 32; off >= 1; off >>= 1) m = fmaxf(m, __shfl_xor(m, off));
    if (lane == 0) red4a[wid] = m;
    __syncthreads();
    const float mc = fmaxf(fmaxf(red4a[0], red4a[1]), fmaxf(red4a[2], red4a[3]));
    const float ec = expf(cc - mc);
    ec_s[tid] = ec;
    float s = ec;
#pragma unroll
    for (int off = 32; off >= 1; off >>= 1) s += __shfl_xor(s, off);
    if (lane == 0) red4b[wid] = s;
    __syncthreads();
    const float Z = red4b[0] + red4b[1] + red4b[2] + red4b[3];

    // ---- phase C: xs0, xs1, xt (wave-per-jj, float2 per lane) ----
    float2 xs0p = {0.f, 0.f}, xs1p = {0.f, 0.f}, xtp = {0.f, 0.f};
    for (int t = 0; t < 64; ++t) {
        const int jj = (t << 2) + wid;
        const float2 xa = *(const float2*)(Xb + jj * 128 + 2 * lane);
        const float2 xb2 = *(const float2*)(Xb + (jj + 256) * 128 + 2 * lane);
        const float e = ec_s[jj];
        xs0p.x += xa.x;  xs0p.y += xa.y;
        xs1p.x += xb2.x; xs1p.y += xb2.y;
        xtp.x = fmaf(e, xa.x + xb2.x, xtp.x);
        xtp.y = fmaf(e, xa.y + xb2.y, xtp.y);
    }
    *(float2*)&xw[0][wid][2 * lane] = xs0p;
    *(float2*)&xw[1][wid][2 * lane] = xs1p;
    *(float2*)&xw[2][wid][2 * lane] = xtp;
    __syncthreads();

#pragma unroll
    for (int r = 0; r < 2; ++r) {
        const int idx = tid + (r << 8);
        if (idx < 384) {
            const int arr = idx >> 7, k = idx & 127;
            xsum[arr][k] = xw[arr][0][k] + xw[arr][1][k] + xw[arr][2][k] + xw[arr][3][k];
        }
    }
    __syncthreads();

    // ---- phase D: S0 = xs0@W, S1 = xs1@W, R2 = (xt@W)/(2Z) ----
    if (wid < 3) {
        float acc0 = 0.f, acc1 = 0.f;
#pragma unroll
        for (int k = 0; k < 128; k += 2) {
            acc0 = fmaf(xsum[wid][k],     W[k * 64 + lane],       acc0);
            acc1 = fmaf(xsum[wid][k + 1], W[(k + 1) * 64 + lane], acc1);
        }
        const float acc = acc0 + acc1;
        Sc[wid][lane] = (wid == 2) ? acc / (2.f * Z) : acc;
    }
    __syncthreads();

    // ---- phase E: finalize own 32 rows ----
    float* outb = out + (b * 512 + chunk * 32) * 64;
    if (chunk < 8) {
        const int i0 = chunk * 32;
#pragma unroll
        for (int it = 0; it < 8; ++it) {
            const int idx = tid + (it << 8);
            const int r = idx >> 6, c = idx & 63;
            const int i = i0 + r;
            float u = p_s[2 * i]     + q_s[2 * i];      // g[2i]
            float v = p_s[2 * i + 1] + q_s[2 * i + 1];  // g[2i+1]
            u = u > 0.f ? u : ALPHA * u;
            v = v > 0.f ? v : ALPHA * v;
            const float m2 = fmaxf(u, v);
            const float w0 = expf(u - m2), w1 = expf(v - m2);
            const float hp = (w0 * Sc[0][c] + w1 * Sc[1][c]) / (256.f * (w0 + w1));
            outb[idx] = hp > 0.f ? hp : expm1f(hp);     // ELU
        }
    } else {
#pragma unroll
        for (int it = 0; it < 8; ++it) {
            const int idx = tid + (it << 8);
            const float hp = Sc[2][idx & 63];
            outb[idx] = hp > 0.f ? hp : expm1f(hp);
        }
    }
}

extern "C" void kernel_launch(void* const* d_in, const int* in_sizes, int n_in,
                              void* d_out, int out_size, void* d_ws, size_t ws_size,
                              hipStream_t stream) {
    const float* X = (const float*)d_in[0];   // (4,512,128)
    // d_in[1] = adj — dead code in the reference
    const float* W = (const float*)d_in[2];   // (128,64)
    const float* a = (const float*)d_in[3];   // (128,1)
    float* out = (float*)d_out;               // (4,512,64)

    hipLaunchKernelGGL(gat_one, dim3(64), dim3(256), 0, stream, X, W, a, out);
}

// Round 4
// 24.788 us; speedup vs baseline: 2.5285x; 1.3954x over previous
//
#include <hip/hip_runtime.h>
#include <math.h>

#define ALPHA 0.2f

// Shapes fixed by harness: B=4, N=512, IN=128, OUT=64.
//
// Algebraic collapse (verified R1-R3, absmax ~5e-4):
//  i < 256 : e[b,i,j] = lrelu(g[b, 2i + (j>=256)]),  g = p + q
//  i >= 256: e[b,i,j] = lrelu(p[b,2*(j%256)] + q[b,2*(j%256)+1]), indep of i
// h = X@W never materialized:
//  p = X·wa1, q = X·wa2          (wa1 = W@a1, wa2 = W@a2)
//  S0 = xs0@W, S1 = xs1@W        (xs0/xs1 = column sums of X row-halves)
//  T  = xt@W,  xt = sum_jj ec[jj]*(x_jj + x_{jj+256});  R2 = T/(2Z)
//
// R3 lesson: 64 blocks x 4 waves = 1 wave/SIMD and rolled loops -> latency
// exposed serially (40us kernel, VALUBusy 1.7%). This version: 4 blocks x
// 16 waves, one block per batch, every phase split across 16 waves with
// unrolled loads. One dispatch, no grid sync, no workspace.

__global__ __launch_bounds__(1024) void gat_block(
    const float* __restrict__ X, const float* __restrict__ W,
    const float* __restrict__ a, float* __restrict__ out)
{
    __shared__ float Ws[128 * 64];        // 32 KB staged W
    __shared__ float a_s[128];
    __shared__ float wp1[128][9], wp2[128][9];   // padded: avoid bank conflicts
    __shared__ float wa1_s[128], wa2_s[128];
    __shared__ float p_s[512], q_s[512];
    __shared__ float ec_s[256];
    __shared__ float red4a[4], red4b[4];
    __shared__ float Zs_s;
    __shared__ float xw[3][16][128];      // per-wave partials of xs0,xs1,xt
    __shared__ float xsum[3][128];
    __shared__ float dpart[3][4][64];
    __shared__ float Sc[3][64];           // S0, S1, R2

    const int tid  = threadIdx.x;
    const int wid  = tid >> 6, lane = tid & 63;
    const int b    = blockIdx.x;          // one block per batch
    const float* Xb = X + b * 512 * 128;

    // ---- stage W (2 float4 per thread) + a ----
    {
        const float4* W4 = (const float4*)W;
        float4* Ws4 = (float4*)Ws;
        Ws4[tid]        = W4[tid];
        Ws4[tid + 1024] = W4[tid + 1024];
        if (tid < 128) a_s[tid] = a[tid];
    }
    __syncthreads();

    // ---- phase 0: wa1 = W@a1, wa2 = W@a2 (128 k x 8 partials) ----
    {
        const int k = tid >> 3, part = tid & 7;
        const float* wr = Ws + k * 64 + part * 8;
        const float* ar = a_s + part * 8;
        float r1 = 0.f, r2 = 0.f;
#pragma unroll
        for (int j = 0; j < 8; ++j) {
            r1 = fmaf(wr[j], ar[j], r1);
            r2 = fmaf(wr[j], ar[64 + j], r2);
        }
        wp1[k][part] = r1;
        wp2[k][part] = r2;
    }
    __syncthreads();
    if (tid < 256) {
        const int k = tid & 127;
        if (tid < 128) {
            float s = 0.f;
#pragma unroll
            for (int j = 0; j < 8; ++j) s += wp1[k][j];
            wa1_s[k] = s;
        } else {
            float s = 0.f;
#pragma unroll
            for (int j = 0; j < 8; ++j) s += wp2[k][j];
            wa2_s[k] = s;
        }
    }
    __syncthreads();

    // ---- phase A: p[j]=x_j·wa1, q[j]=x_j·wa2 (2 threads/row, half-dots) ----
    {
        const int row = tid >> 1, half = tid & 1;
        const float4* xr = (const float4*)(Xb + row * 128 + half * 64);
        const float4* w1 = (const float4*)(wa1_s + half * 64);
        const float4* w2 = (const float4*)(wa2_s + half * 64);
        float pp = 0.f, qq = 0.f;
#pragma unroll
        for (int k4 = 0; k4 < 16; ++k4) {
            const float4 x4 = xr[k4];
            const float4 v1 = w1[k4];
            const float4 v2 = w2[k4];
            pp = fmaf(x4.x, v1.x, pp); pp = fmaf(x4.y, v1.y, pp);
            pp = fmaf(x4.z, v1.z, pp); pp = fmaf(x4.w, v1.w, pp);
            qq = fmaf(x4.x, v2.x, qq); qq = fmaf(x4.y, v2.y, qq);
            qq = fmaf(x4.z, v2.z, qq); qq = fmaf(x4.w, v2.w, qq);
        }
        pp += __shfl_xor(pp, 1);       // combine the two half-dots
        qq += __shfl_xor(qq, 1);
        if (half == 0) { p_s[row] = pp; q_s[row] = qq; }
    }
    __syncthreads();

    // ---- phase B: softmax over cc[jj] = lrelu(p[2jj] + q[2jj+1]) ----
    float cc = 0.f;
    if (tid < 256) {
        cc = p_s[2 * tid] + q_s[2 * tid + 1];
        cc = cc > 0.f ? cc : ALPHA * cc;
        float m = cc;
#pragma unroll
        for (int off = 32; off >= 1; off >>= 1) m = fmaxf(m, __shfl_xor(m, off));
        if (lane == 0) red4a[wid] = m;
    }
    __syncthreads();
    if (tid < 256) {
        const float mc = fmaxf(fmaxf(red4a[0], red4a[1]), fmaxf(red4a[2], red4a[3]));
        const float ec = expf(cc - mc);
        ec_s[tid] = ec;
        float s = ec;
#pragma unroll
        for (int off = 32; off >= 1; off >>= 1) s += __shfl_xor(s, off);
        if (lane == 0) red4b[wid] = s;
    }
    __syncthreads();
    if (tid == 0) Zs_s = red4b[0] + red4b[1] + red4b[2] + red4b[3];
    // Zs_s consumed only after the phase-C syncs below.

    // ---- phase C: xs0,xs1,xt partials (wave w owns 16 jj rows) ----
    {
        float2 xs0p = {0.f, 0.f}, xs1p = {0.f, 0.f}, xtp = {0.f, 0.f};
        const float* x0 = Xb + (wid * 16) * 128 + 2 * lane;
#pragma unroll 4
        for (int i = 0; i < 16; ++i) {
            const int jj = wid * 16 + i;
            const float2 xa  = *(const float2*)(x0 + i * 128);
            const float2 xb2 = *(const float2*)(x0 + (i + 256) * 128);
            const float e = ec_s[jj];
            xs0p.x += xa.x;   xs0p.y += xa.y;
            xs1p.x += xb2.x;  xs1p.y += xb2.y;
            xtp.x = fmaf(e, xa.x + xb2.x, xtp.x);
            xtp.y = fmaf(e, xa.y + xb2.y, xtp.y);
        }
        *(float2*)&xw[0][wid][2 * lane] = xs0p;
        *(float2*)&xw[1][wid][2 * lane] = xs1p;
        *(float2*)&xw[2][wid][2 * lane] = xtp;
    }
    __syncthreads();
    if (tid < 384) {
        const int arr = tid >> 7, k = tid & 127;
        float s = 0.f;
#pragma unroll
        for (int j = 0; j < 16; ++j) s += xw[arr][j][k];
        xsum[arr][k] = s;
    }
    __syncthreads();

    // ---- phase D: S0=xs0@W, S1=xs1@W, R2=(xt@W)/(2Z) (12 waves) ----
    if (wid < 12) {
        const int g = wid >> 2, kq = wid & 3;
        float acc = 0.f;
#pragma unroll
        for (int i = 0; i < 32; ++i) {
            const int k = kq * 32 + i;
            acc = fmaf(xsum[g][k], Ws[k * 64 + lane], acc);
        }
        dpart[g][kq][lane] = acc;
    }
    __syncthreads();
    if (tid < 192) {
        const int g = tid >> 6, c = tid & 63;
        float s = dpart[g][0][c] + dpart[g][1][c] + dpart[g][2][c] + dpart[g][3][c];
        if (g == 2) s /= (2.f * Zs_s);
        Sc[g][c] = s;
    }
    __syncthreads();

    // ---- phase E: finalize all 512 rows (half-row per thread) ----
    {
        const int i = tid >> 1, co = (tid & 1) << 5;
        float* orow = out + (b * 512 + i) * 64 + co;
        if (i < 256) {
            float u = p_s[2 * i]     + q_s[2 * i];
            float v = p_s[2 * i + 1] + q_s[2 * i + 1];
            u = u > 0.f ? u : ALPHA * u;
            v = v > 0.f ? v : ALPHA * v;
            const float m2 = fmaxf(u, v);
            const float w0 = expf(u - m2), w1 = expf(v - m2);
            const float inv = 1.0f / (256.f * (w0 + w1));
#pragma unroll
            for (int j = 0; j < 8; ++j) {
                const float4 s0 = *(const float4*)&Sc[0][co + 4 * j];
                const float4 s1 = *(const float4*)&Sc[1][co + 4 * j];
                float4 hp;
                hp.x = (w0 * s0.x + w1 * s1.x) * inv;
                hp.y = (w0 * s0.y + w1 * s1.y) * inv;
                hp.z = (w0 * s0.z + w1 * s1.z) * inv;
                hp.w = (w0 * s0.w + w1 * s1.w) * inv;
                hp.x = hp.x > 0.f ? hp.x : expm1f(hp.x);
                hp.y = hp.y > 0.f ? hp.y : expm1f(hp.y);
                hp.z = hp.z > 0.f ? hp.z : expm1f(hp.z);
                hp.w = hp.w > 0.f ? hp.w : expm1f(hp.w);
                *(float4*)&orow[4 * j] = hp;
            }
        } else {
#pragma unroll
            for (int j = 0; j < 8; ++j) {
                const float4 s2 = *(const float4*)&Sc[2][co + 4 * j];
                float4 hp;
                hp.x = s2.x > 0.f ? s2.x : expm1f(s2.x);
                hp.y = s2.y > 0.f ? s2.y : expm1f(s2.y);
                hp.z = s2.z > 0.f ? s2.z : expm1f(s2.z);
                hp.w = s2.w > 0.f ? s2.w : expm1f(s2.w);
                *(float4*)&orow[4 * j] = hp;
            }
        }
    }
}

extern "C" void kernel_launch(void* const* d_in, const int* in_sizes, int n_in,
                              void* d_out, int out_size, void* d_ws, size_t ws_size,
                              hipStream_t stream) {
    const float* X = (const float*)d_in[0];   // (4,512,128)
    // d_in[1] = adj — dead code in the reference
    const float* W = (const float*)d_in[2];   // (128,64)
    const float* a = (const float*)d_in[3];   // (128,1)
    float* out = (float*)d_out;               // (4,512,64)

    hipLaunchKernelGGL(gat_block, dim3(4), dim3(1024), 0, stream, X, W, a, out);
}